// Round 1
// baseline (1185.617 us; speedup 1.0000x reference)
//
#include <hip/hip_runtime.h>
#include <hip/hip_bf16.h>

#define NND 50000
#define NCATS 3
#define VOC 1000
#define EDIM 16
#define NNUMF 16
#define FMAP 32
#define FIN 128          // 3*16 + 16 + 64
#define HID 64
#define NH 4
#define EB 400000
#define ETOT 450000      // EB + NND self loops
#define M1 256
#define M2 128
#define EPS_BN 1e-5f

__device__ __forceinline__ float lrelu(float x) { return x > 0.f ? x : 0.2f * x; }

// monotone unsigned encoding for float atomicMax
__device__ __forceinline__ unsigned enc_f(float x) {
    unsigned u = __float_as_uint(x);
    return (u & 0x80000000u) ? ~u : (u | 0x80000000u);
}
__device__ __forceinline__ float dec_f(unsigned u) {
    return __uint_as_float((u & 0x80000000u) ? (u ^ 0x80000000u) : ~u);
}

// ---------------- K1: featurize + project (128 -> 64) ----------------
__global__ __launch_bounds__(256) void k_feat_proj(
    const int* __restrict__ x_cat, const float* __restrict__ x_num,
    const float* __restrict__ x_coord, const float* __restrict__ emb,
    const float* __restrict__ fB, const float* __restrict__ pW,
    const float* __restrict__ pb, float* __restrict__ xout)
{
    __shared__ float Wl[FIN * HID];   // 32 KB
    __shared__ float feat[4][FIN];
    const int tid = threadIdx.x;
    for (int i = tid; i < FIN * HID; i += 256) Wl[i] = pW[i];
    __syncthreads();
    const int wid = tid >> 6, lane = tid & 63;
    const int ngroups = (NND + 3) / 4;
    for (int g = blockIdx.x; g < ngroups; g += gridDim.x) {
        const int n = g * 4 + wid;
        if (n < NND) {
            float v;
            if (lane < 48) {
                int c = lane >> 4, j = lane & 15;
                int idx = x_cat[n * NCATS + c];
                v = emb[((size_t)c * VOC + idx) * EDIM + j];
            } else {
                v = x_num[n * NNUMF + (lane - 48)];
            }
            feat[wid][lane] = v;
            float c0 = x_coord[n * 2 + 0], c1 = x_coord[n * 2 + 1];
            int f = lane & 31;
            float xp = 6.283185307179586f * (c0 * fB[f] + c1 * fB[FMAP + f]);
            feat[wid][64 + lane] = (lane < 32) ? sinf(xp) : cosf(xp);
        }
        __syncthreads();
        if (n < NND) {
            float acc = pb[lane];
            #pragma unroll 8
            for (int k = 0; k < FIN; ++k)
                acc = fmaf(feat[wid][k], Wl[k * HID + lane], acc);
            xout[(size_t)n * HID + lane] = acc;
        }
        __syncthreads();
    }
}

// ---------------- K2: h = x @ gatW (64 -> 256) + alphas ----------------
__global__ __launch_bounds__(256) void k_gat_h(
    const float* __restrict__ x, const float* __restrict__ W,
    const float* __restrict__ asrcW, const float* __restrict__ adstW,
    float* __restrict__ h, float* __restrict__ alphS, float* __restrict__ alphD)
{
    __shared__ float Wl[HID * 256];   // 64 KB
    __shared__ float xr[HID];
    const int tid = threadIdx.x;
    for (int i = tid; i < HID * 256; i += 256) Wl[i] = W[i];
    __syncthreads();
    const int wid = tid >> 6, lane = tid & 63;
    for (int n = blockIdx.x; n < NND; n += gridDim.x) {
        if (tid < HID) xr[tid] = x[(size_t)n * HID + tid];
        __syncthreads();
        float acc = 0.f;
        #pragma unroll 8
        for (int k = 0; k < HID; ++k)
            acc = fmaf(xr[k], Wl[k * 256 + tid], acc);
        h[(size_t)n * 256 + tid] = acc;
        float s = acc * asrcW[wid * HID + lane];
        float d = acc * adstW[wid * HID + lane];
        #pragma unroll
        for (int off = 32; off; off >>= 1) {
            s += __shfl_xor(s, off, 64);
            d += __shfl_xor(d, off, 64);
        }
        if (lane == 0) {
            alphS[n * NH + wid] = s;
            alphD[n * NH + wid] = d;
        }
        __syncthreads();
    }
}

// ---------------- init per layer ----------------
__global__ void k_init(float* __restrict__ accum, unsigned* __restrict__ smax,
                       float* __restrict__ ssum, float* __restrict__ bnst)
{
    for (int i = blockIdx.x * blockDim.x + threadIdx.x; i < NND * HID;
         i += gridDim.x * blockDim.x) {
        accum[i] = 0.f;
        if (i < NND * NH) { smax[i] = 0x007FFFFFu; ssum[i] = 0.f; }
        if (i < 128) bnst[i] = 0.f;
    }
}

// ---------------- K3: segment max over edges ----------------
__global__ void k_edge_max(const int* __restrict__ ei, const float* __restrict__ as_,
                           const float* __restrict__ ad_, unsigned* __restrict__ smax)
{
    for (int e = blockIdx.x * blockDim.x + threadIdx.x; e < ETOT;
         e += gridDim.x * blockDim.x) {
        int s, d;
        if (e < EB) { s = ei[e]; d = ei[EB + e]; } else { s = d = e - EB; }
        float4 a = *(const float4*)(as_ + (size_t)s * 4);
        float4 b = *(const float4*)(ad_ + (size_t)d * 4);
        atomicMax(smax + (size_t)d * 4 + 0, enc_f(lrelu(a.x + b.x)));
        atomicMax(smax + (size_t)d * 4 + 1, enc_f(lrelu(a.y + b.y)));
        atomicMax(smax + (size_t)d * 4 + 2, enc_f(lrelu(a.z + b.z)));
        atomicMax(smax + (size_t)d * 4 + 3, enc_f(lrelu(a.w + b.w)));
    }
}

// ---------------- K4: segment sum of exp ----------------
__global__ void k_edge_sum(const int* __restrict__ ei, const float* __restrict__ as_,
                           const float* __restrict__ ad_, const unsigned* __restrict__ smax,
                           float* __restrict__ ssum)
{
    for (int e = blockIdx.x * blockDim.x + threadIdx.x; e < ETOT;
         e += gridDim.x * blockDim.x) {
        int s, d;
        if (e < EB) { s = ei[e]; d = ei[EB + e]; } else { s = d = e - EB; }
        float4 a = *(const float4*)(as_ + (size_t)s * 4);
        float4 b = *(const float4*)(ad_ + (size_t)d * 4);
        uint4 mu = *(const uint4*)(smax + (size_t)d * 4);
        atomicAdd(ssum + (size_t)d * 4 + 0, __expf(lrelu(a.x + b.x) - dec_f(mu.x)));
        atomicAdd(ssum + (size_t)d * 4 + 1, __expf(lrelu(a.y + b.y) - dec_f(mu.y)));
        atomicAdd(ssum + (size_t)d * 4 + 2, __expf(lrelu(a.z + b.z) - dec_f(mu.z)));
        atomicAdd(ssum + (size_t)d * 4 + 3, __expf(lrelu(a.w + b.w) - dec_f(mu.w)));
    }
}

// ---------------- K5: weighted scatter (wave per edge, lane = dim) ----------------
__global__ __launch_bounds__(256) void k_edge_scatter(
    const int* __restrict__ ei, const float* __restrict__ as_,
    const float* __restrict__ ad_, const unsigned* __restrict__ smax,
    const float* __restrict__ ssum, const float* __restrict__ h,
    float* __restrict__ accum)
{
    const int lane = threadIdx.x & 63;
    int gw = blockIdx.x * 4 + (threadIdx.x >> 6);
    const int nw = gridDim.x * 4;
    for (int e = gw; e < ETOT; e += nw) {
        int s, d;
        if (e < EB) { s = ei[e]; d = ei[EB + e]; } else { s = d = e - EB; }
        float4 a = *(const float4*)(as_ + (size_t)s * 4);
        float4 b = *(const float4*)(ad_ + (size_t)d * 4);
        uint4 mu = *(const uint4*)(smax + (size_t)d * 4);
        float4 dn = *(const float4*)(ssum + (size_t)d * 4);
        float w0 = __expf(lrelu(a.x + b.x) - dec_f(mu.x)) / (dn.x + 1e-16f);
        float w1 = __expf(lrelu(a.y + b.y) - dec_f(mu.y)) / (dn.y + 1e-16f);
        float w2 = __expf(lrelu(a.z + b.z) - dec_f(mu.z)) / (dn.z + 1e-16f);
        float w3 = __expf(lrelu(a.w + b.w) - dec_f(mu.w)) / (dn.w + 1e-16f);
        const float* hs = h + (size_t)s * 256;
        float val = w0 * hs[lane] + w1 * hs[64 + lane] + w2 * hs[128 + lane]
                  + w3 * hs[192 + lane];
        atomicAdd(accum + (size_t)d * HID + lane, val);
    }
}

// ---------------- K6: finalize (mean over heads + bias) + BN stats ----------------
__global__ __launch_bounds__(256) void k_gat_fin(
    float* __restrict__ accum, const float* __restrict__ gat_b, float* __restrict__ bnst)
{
    const int tid = threadIdx.x;
    const int d = tid & 63;
    float s1 = 0.f, s2 = 0.f;
    const float bd = gat_b[d];
    for (int i = blockIdx.x * 256 + tid; i < NND * HID; i += gridDim.x * 256) {
        float g = accum[i] * 0.25f + bd;
        accum[i] = g;
        s1 += g;
        s2 += g * g;
    }
    __shared__ float red[2][256];
    red[0][tid] = s1; red[1][tid] = s2;
    __syncthreads();
    if (tid < 64) {
        s1 = red[0][tid] + red[0][tid + 64] + red[0][tid + 128] + red[0][tid + 192];
        s2 = red[1][tid] + red[1][tid + 64] + red[1][tid + 128] + red[1][tid + 192];
        atomicAdd(&bnst[d], s1);
        atomicAdd(&bnst[64 + d], s2);
    }
}

// ---------------- K7: BN apply + relu + residual (in place on x) ----------------
__global__ void k_bn_apply(const float* __restrict__ accum, const float* __restrict__ bnst,
                           const float* __restrict__ gamma, const float* __restrict__ beta,
                           float* __restrict__ x)
{
    int i = blockIdx.x * blockDim.x + threadIdx.x;
    if (i >= NND * HID) return;
    int d = i & 63;
    float mu = bnst[d] * (1.f / NND);
    float var = bnst[64 + d] * (1.f / NND) - mu * mu;
    float inv = rsqrtf(var + EPS_BN);
    float y = (accum[i] - mu) * inv * gamma[d] + beta[d];
    y = fmaxf(y, 0.f);
    x[i] = y + x[i];
}

// ---------------- K8: z1 = relu(x @ W1 + b1) (64 -> 256) ----------------
__global__ __launch_bounds__(256) void k_mlp1(
    const float* __restrict__ x, const float* __restrict__ W1,
    const float* __restrict__ b1, float* __restrict__ z1)
{
    __shared__ float Wl[HID * M1];   // 64 KB
    __shared__ float xr[HID];
    const int tid = threadIdx.x;
    for (int i = tid; i < HID * M1; i += 256) Wl[i] = W1[i];
    __syncthreads();
    for (int n = blockIdx.x; n < NND; n += gridDim.x) {
        if (tid < HID) xr[tid] = x[(size_t)n * HID + tid];
        __syncthreads();
        float acc = b1[tid];
        #pragma unroll 8
        for (int k = 0; k < HID; ++k)
            acc = fmaf(xr[k], Wl[k * M1 + tid], acc);
        z1[(size_t)n * M1 + tid] = fmaxf(acc, 0.f);
        __syncthreads();
    }
}

// ---------------- K9: fused z2 = relu(z1 @ W2 + b2); out = z2 @ W3 + b3 ----------------
__global__ __launch_bounds__(256) void k_mlp23(
    const float* __restrict__ z1, const float* __restrict__ W2,
    const float* __restrict__ b2, const float* __restrict__ W3,
    const float* __restrict__ b3, float* __restrict__ out)
{
    __shared__ float z1s[16][M1];   // 16 KB
    __shared__ float Wt[64 * M2];   // 32 KB
    __shared__ float z2s[16][M2];   // 8 KB
    const int tid = threadIdx.x;
    const int j = tid & 127, nsub = tid >> 7;
    const int ngroups = (NND + 15) / 16;
    for (int g = blockIdx.x; g < ngroups; g += gridDim.x) {
        const int n0 = g * 16;
        for (int i = tid; i < 16 * M1 / 4; i += 256) {
            int nn = i >> 6;
            int kk = (i & 63) * 4;
            int n = n0 + nn;
            float4 v = (n < NND) ? *(const float4*)(z1 + (size_t)n * M1 + kk)
                                 : make_float4(0.f, 0.f, 0.f, 0.f);
            *(float4*)&z1s[nn][kk] = v;
        }
        float acc[8];
        #pragma unroll
        for (int r = 0; r < 8; ++r) acc[r] = b2[j];
        for (int kt = 0; kt < 4; ++kt) {
            __syncthreads();
            for (int i = tid; i < 64 * M2 / 4; i += 256) {
                int row = (i * 4) >> 7;
                int col = (i * 4) & 127;
                *(float4*)&Wt[row * M2 + col] =
                    *(const float4*)(W2 + (size_t)(kt * 64 + row) * M2 + col);
            }
            __syncthreads();
            #pragma unroll 4
            for (int k = 0; k < 64; ++k) {
                float wv = Wt[k * M2 + j];
                #pragma unroll
                for (int r = 0; r < 8; ++r)
                    acc[r] = fmaf(z1s[nsub + 2 * r][kt * 64 + k], wv, acc[r]);
            }
        }
        #pragma unroll
        for (int r = 0; r < 8; ++r) z2s[nsub + 2 * r][j] = fmaxf(acc[r], 0.f);
        __syncthreads();
        const int wid = tid >> 6, lane = tid & 63;
        for (int nl = wid; nl < 16; nl += 4) {
            float sv = W3[lane] * z2s[nl][lane] + W3[64 + lane] * z2s[nl][64 + lane];
            #pragma unroll
            for (int off = 32; off; off >>= 1) sv += __shfl_xor(sv, off, 64);
            if (lane == 0) {
                int n = n0 + nl;
                if (n < NND) out[n] = sv + b3[0];
            }
        }
        __syncthreads();
    }
}

extern "C" void kernel_launch(void* const* d_in, const int* in_sizes, int n_in,
                              void* d_out, int out_size, void* d_ws, size_t ws_size,
                              hipStream_t stream) {
    const int*   x_cat   = (const int*)  d_in[0];
    const float* x_num   = (const float*)d_in[1];
    const float* x_coord = (const float*)d_in[2];
    const int*   eidx    = (const int*)  d_in[3];
    const float* emb     = (const float*)d_in[4];
    const float* fB      = (const float*)d_in[5];
    const float* pW      = (const float*)d_in[6];
    const float* pb      = (const float*)d_in[7];
    const float* gatW    = (const float*)d_in[8];
    const float* attS    = (const float*)d_in[9];
    const float* attD    = (const float*)d_in[10];
    const float* gatB    = (const float*)d_in[11];
    const float* bnG     = (const float*)d_in[12];
    const float* bnB     = (const float*)d_in[13];
    const float* W1      = (const float*)d_in[14];
    const float* b1      = (const float*)d_in[15];
    const float* W2      = (const float*)d_in[16];
    const float* b2      = (const float*)d_in[17];
    const float* W3      = (const float*)d_in[18];
    const float* b3      = (const float*)d_in[19];
    float* out = (float*)d_out;

    char* p = (char*)d_ws;
    float*    x     = (float*)p;    p += (size_t)NND * HID * 4;
    float*    h     = (float*)p;    p += (size_t)NND * 256 * 4;
    float*    alphS = (float*)p;    p += (size_t)NND * NH * 4;
    float*    alphD = (float*)p;    p += (size_t)NND * NH * 4;
    unsigned* smax  = (unsigned*)p; p += (size_t)NND * NH * 4;
    float*    ssum  = (float*)p;    p += (size_t)NND * NH * 4;
    float*    accum = (float*)p;    p += (size_t)NND * HID * 4;
    float*    bnst  = (float*)p;    p += 512;

    k_feat_proj<<<512, 256, 0, stream>>>(x_cat, x_num, x_coord, emb, fB, pW, pb, x);
    for (int l = 0; l < 2; ++l) {
        k_gat_h<<<512, 256, 0, stream>>>(x, gatW + (size_t)l * HID * 256,
                                         attS + l * NH * HID, attD + l * NH * HID,
                                         h, alphS, alphD);
        k_init<<<2048, 256, 0, stream>>>(accum, smax, ssum, bnst);
        k_edge_max<<<2048, 256, 0, stream>>>(eidx, alphS, alphD, smax);
        k_edge_sum<<<2048, 256, 0, stream>>>(eidx, alphS, alphD, smax, ssum);
        k_edge_scatter<<<8192, 256, 0, stream>>>(eidx, alphS, alphD, smax, ssum, h, accum);
        k_gat_fin<<<1024, 256, 0, stream>>>(accum, gatB + l * HID, bnst);
        k_bn_apply<<<12500, 256, 0, stream>>>(accum, bnst, bnG + l * HID, bnB + l * HID, x);
    }
    k_mlp1<<<512, 256, 0, stream>>>(x, W1, b1, h);
    k_mlp23<<<512, 256, 0, stream>>>(h, W2, b2, W3, b3, out);
}

// Round 2
// 847.573 us; speedup vs baseline: 1.3988x; 1.3988x over previous
//
#include <hip/hip_runtime.h>
#include <hip/hip_bf16.h>

#define NND 50000
#define NCATS 3
#define VOC 1000
#define EDIM 16
#define NNUMF 16
#define FMAP 32
#define FIN 128          // 3*16 + 16 + 64
#define HID 64
#define NH 4
#define EB 400000
#define ETOT 450000      // EB + NND self loops
#define M1 256
#define M2 128
#define EPS_BN 1e-5f

__device__ __forceinline__ float lrelu(float x) { return x > 0.f ? x : 0.2f * x; }

// ---------------- K1: featurize + project (128 -> 64), 16-node tiles ----------------
__global__ __launch_bounds__(256) void k_feat_proj(
    const int* __restrict__ x_cat, const float* __restrict__ x_num,
    const float* __restrict__ x_coord, const float* __restrict__ emb,
    const float* __restrict__ fB, const float* __restrict__ pW,
    const float* __restrict__ pb, float* __restrict__ xout)
{
    __shared__ float Wl[FIN * HID];   // 32 KB
    __shared__ float feat[16][FIN];   // 8 KB
    const int tid = threadIdx.x;
    for (int i = tid; i < FIN * HID; i += 256) Wl[i] = pW[i];
    const int wid = tid >> 6, lane = tid & 63;
    const int col = lane, ng = wid;
    const float bias = pb[col];
    const int ntiles = NND / 16;      // 50000 = 16*3125 exactly
    for (int t = blockIdx.x; t < ntiles; t += gridDim.x) {
        const int n0 = t * 16;
        __syncthreads();
        #pragma unroll
        for (int r = 0; r < 4; ++r) {
            const int nn = wid * 4 + r;
            const int n = n0 + nn;
            float v;
            if (lane < 48) {
                int c = lane >> 4, j = lane & 15;
                int idx = x_cat[n * NCATS + c];
                v = emb[((size_t)c * VOC + idx) * EDIM + j];
            } else {
                v = x_num[n * NNUMF + (lane - 48)];
            }
            feat[nn][lane] = v;
            float c0 = x_coord[n * 2 + 0], c1 = x_coord[n * 2 + 1];
            int f = lane & 31;
            float xp = 6.283185307179586f * (c0 * fB[f] + c1 * fB[FMAP + f]);
            feat[nn][64 + lane] = (lane < 32) ? sinf(xp) : cosf(xp);
        }
        __syncthreads();
        float acc[4] = {bias, bias, bias, bias};
        #pragma unroll 4
        for (int k = 0; k < FIN; ++k) {
            float w = Wl[k * HID + col];
            #pragma unroll
            for (int j = 0; j < 4; ++j)
                acc[j] = fmaf(feat[ng + 4 * j][k], w, acc[j]);
        }
        #pragma unroll
        for (int j = 0; j < 4; ++j)
            xout[(size_t)(n0 + ng + 4 * j) * HID + col] = acc[j];
    }
}

// ---------------- K2: h = x @ gatW (64 -> 256), 16-node register tiles ----------------
__global__ __launch_bounds__(256) void k_gat_h(
    const float* __restrict__ x, const float* __restrict__ W,
    float* __restrict__ h)
{
    __shared__ float Wl[HID * 256];   // 64 KB
    __shared__ float xs[16][HID];     // 4 KB
    const int tid = threadIdx.x;
    for (int i = tid; i < HID * 256; i += 256) Wl[i] = W[i];
    const int ntiles = NND / 16;
    for (int t = blockIdx.x; t < ntiles; t += gridDim.x) {
        const int n0 = t * 16;
        __syncthreads();
        {
            int idx = tid * 4;            // 0..1023
            int nn = idx >> 6, k = idx & 63;
            float4 v = *(const float4*)(x + (size_t)(n0 + nn) * HID + k);
            xs[nn][k] = v.x; xs[nn][k + 1] = v.y; xs[nn][k + 2] = v.z; xs[nn][k + 3] = v.w;
        }
        __syncthreads();
        float acc[16];
        #pragma unroll
        for (int nn = 0; nn < 16; ++nn) acc[nn] = 0.f;
        #pragma unroll 4
        for (int k = 0; k < HID; ++k) {
            float w = Wl[k * 256 + tid];
            #pragma unroll
            for (int nn = 0; nn < 16; ++nn)
                acc[nn] = fmaf(xs[nn][k], w, acc[nn]);
        }
        #pragma unroll
        for (int nn = 0; nn < 16; ++nn)
            h[(size_t)(n0 + nn) * 256 + tid] = acc[nn];
    }
}

// ---------------- K2b: alpha_src/dst = per-head dot(h, a) ----------------
__global__ __launch_bounds__(256) void k_alpha(
    const float* __restrict__ h, const float* __restrict__ asrcW,
    const float* __restrict__ adstW, float* __restrict__ alphS,
    float* __restrict__ alphD)
{
    __shared__ float aS[256], aD[256];
    const int tid = threadIdx.x;
    aS[tid] = asrcW[tid];
    aD[tid] = adstW[tid];
    __syncthreads();
    const int wid = tid >> 6, lane = tid & 63;
    const int gw = blockIdx.x * 4 + wid, nw = gridDim.x * 4;
    for (int n = gw; n < NND; n += nw) {
        float s0, s1, s2, s3, d0, d1, d2, d3;
        {
            float v0 = h[(size_t)n * 256 + 0 * 64 + lane];
            float v1 = h[(size_t)n * 256 + 1 * 64 + lane];
            float v2 = h[(size_t)n * 256 + 2 * 64 + lane];
            float v3 = h[(size_t)n * 256 + 3 * 64 + lane];
            s0 = v0 * aS[0 * 64 + lane]; d0 = v0 * aD[0 * 64 + lane];
            s1 = v1 * aS[1 * 64 + lane]; d1 = v1 * aD[1 * 64 + lane];
            s2 = v2 * aS[2 * 64 + lane]; d2 = v2 * aD[2 * 64 + lane];
            s3 = v3 * aS[3 * 64 + lane]; d3 = v3 * aD[3 * 64 + lane];
        }
        #pragma unroll
        for (int off = 32; off; off >>= 1) {
            s0 += __shfl_xor(s0, off, 64); d0 += __shfl_xor(d0, off, 64);
            s1 += __shfl_xor(s1, off, 64); d1 += __shfl_xor(d1, off, 64);
            s2 += __shfl_xor(s2, off, 64); d2 += __shfl_xor(d2, off, 64);
            s3 += __shfl_xor(s3, off, 64); d3 += __shfl_xor(d3, off, 64);
        }
        if (lane == 0) {
            *(float4*)(alphS + (size_t)n * 4) = make_float4(s0, s1, s2, s3);
            *(float4*)(alphD + (size_t)n * 4) = make_float4(d0, d1, d2, d3);
        }
    }
}

// ---------------- init per layer ----------------
__global__ void k_init(float* __restrict__ accum, float* __restrict__ ssum,
                       float* __restrict__ bnst)
{
    for (int i = blockIdx.x * blockDim.x + threadIdx.x; i < NND * HID;
         i += gridDim.x * blockDim.x) {
        accum[i] = 0.f;
        if (i < NND * NH) ssum[i] = 0.f;
        if (i < 128) bnst[i] = 0.f;
    }
}

// ---------------- K4: segment sum of exp (no max shift; logits bounded) ----------------
__global__ __launch_bounds__(256) void k_edge_sum(
    const int* __restrict__ ei, const float* __restrict__ as_,
    const float* __restrict__ ad_, float* __restrict__ ssum)
{
    int e = blockIdx.x * blockDim.x + threadIdx.x;
    if (e >= ETOT) return;
    int s, d;
    if (e < EB) { s = ei[e]; d = ei[EB + e]; } else { s = d = e - EB; }
    float4 a = *(const float4*)(as_ + (size_t)s * 4);
    float4 b = *(const float4*)(ad_ + (size_t)d * 4);
    atomicAdd(ssum + (size_t)d * 4 + 0, __expf(lrelu(a.x + b.x)));
    atomicAdd(ssum + (size_t)d * 4 + 1, __expf(lrelu(a.y + b.y)));
    atomicAdd(ssum + (size_t)d * 4 + 2, __expf(lrelu(a.z + b.z)));
    atomicAdd(ssum + (size_t)d * 4 + 3, __expf(lrelu(a.w + b.w)));
}

// ---------------- K5: weighted scatter (wave per edge, lane = dim) ----------------
__global__ __launch_bounds__(256) void k_edge_scatter(
    const int* __restrict__ ei, const float* __restrict__ as_,
    const float* __restrict__ ad_, const float* __restrict__ ssum,
    const float* __restrict__ h, float* __restrict__ accum)
{
    const int lane = threadIdx.x & 63;
    int gw = blockIdx.x * 4 + (threadIdx.x >> 6);
    const int nw = gridDim.x * 4;
    for (int e = gw; e < ETOT; e += nw) {
        int s, d;
        if (e < EB) { s = ei[e]; d = ei[EB + e]; } else { s = d = e - EB; }
        float4 a = *(const float4*)(as_ + (size_t)s * 4);
        float4 b = *(const float4*)(ad_ + (size_t)d * 4);
        float4 dn = *(const float4*)(ssum + (size_t)d * 4);
        float w0 = __expf(lrelu(a.x + b.x)) * __fdividef(1.f, dn.x + 1e-16f);
        float w1 = __expf(lrelu(a.y + b.y)) * __fdividef(1.f, dn.y + 1e-16f);
        float w2 = __expf(lrelu(a.z + b.z)) * __fdividef(1.f, dn.z + 1e-16f);
        float w3 = __expf(lrelu(a.w + b.w)) * __fdividef(1.f, dn.w + 1e-16f);
        const float* hs = h + (size_t)s * 256;
        float val = w0 * hs[lane] + w1 * hs[64 + lane] + w2 * hs[128 + lane]
                  + w3 * hs[192 + lane];
        atomicAdd(accum + (size_t)d * HID + lane, val);
    }
}

// ---------------- K6: finalize (mean over heads + bias) + BN stats ----------------
__global__ __launch_bounds__(256) void k_gat_fin(
    float* __restrict__ accum, const float* __restrict__ gat_b, float* __restrict__ bnst)
{
    const int tid = threadIdx.x;
    const int d = tid & 63;
    float s1 = 0.f, s2 = 0.f;
    const float bd = gat_b[d];
    for (int i = blockIdx.x * 256 + tid; i < NND * HID; i += gridDim.x * 256) {
        float g = accum[i] * 0.25f + bd;
        accum[i] = g;
        s1 += g;
        s2 += g * g;
    }
    __shared__ float red[2][256];
    red[0][tid] = s1; red[1][tid] = s2;
    __syncthreads();
    if (tid < 64) {
        s1 = red[0][tid] + red[0][tid + 64] + red[0][tid + 128] + red[0][tid + 192];
        s2 = red[1][tid] + red[1][tid + 64] + red[1][tid + 128] + red[1][tid + 192];
        atomicAdd(&bnst[d], s1);
        atomicAdd(&bnst[64 + d], s2);
    }
}

// ---------------- K7: BN apply + relu + residual (in place on x) ----------------
__global__ void k_bn_apply(const float* __restrict__ accum, const float* __restrict__ bnst,
                           const float* __restrict__ gamma, const float* __restrict__ beta,
                           float* __restrict__ x)
{
    int i = blockIdx.x * blockDim.x + threadIdx.x;
    if (i >= NND * HID) return;
    int d = i & 63;
    float mu = bnst[d] * (1.f / NND);
    float var = bnst[64 + d] * (1.f / NND) - mu * mu;
    float inv = rsqrtf(var + EPS_BN);
    float y = (accum[i] - mu) * inv * gamma[d] + beta[d];
    y = fmaxf(y, 0.f);
    x[i] = y + x[i];
}

// ---------------- K8: z1 = relu(x @ W1 + b1) (64 -> 256), 16-node tiles ----------------
__global__ __launch_bounds__(256) void k_mlp1(
    const float* __restrict__ x, const float* __restrict__ W1,
    const float* __restrict__ b1, float* __restrict__ z1)
{
    __shared__ float Wl[HID * M1];    // 64 KB
    __shared__ float xs[16][HID];     // 4 KB
    const int tid = threadIdx.x;
    for (int i = tid; i < HID * M1; i += 256) Wl[i] = W1[i];
    const float bias = b1[tid];
    const int ntiles = NND / 16;
    for (int t = blockIdx.x; t < ntiles; t += gridDim.x) {
        const int n0 = t * 16;
        __syncthreads();
        {
            int idx = tid * 4;
            int nn = idx >> 6, k = idx & 63;
            float4 v = *(const float4*)(x + (size_t)(n0 + nn) * HID + k);
            xs[nn][k] = v.x; xs[nn][k + 1] = v.y; xs[nn][k + 2] = v.z; xs[nn][k + 3] = v.w;
        }
        __syncthreads();
        float acc[16];
        #pragma unroll
        for (int nn = 0; nn < 16; ++nn) acc[nn] = bias;
        #pragma unroll 4
        for (int k = 0; k < HID; ++k) {
            float w = Wl[k * M1 + tid];
            #pragma unroll
            for (int nn = 0; nn < 16; ++nn)
                acc[nn] = fmaf(xs[nn][k], w, acc[nn]);
        }
        #pragma unroll
        for (int nn = 0; nn < 16; ++nn)
            z1[(size_t)(n0 + nn) * M1 + tid] = fmaxf(acc[nn], 0.f);
    }
}

// ---------------- K9: fused z2 = relu(z1 @ W2 + b2); out = z2 @ W3 + b3 ----------------
__global__ __launch_bounds__(256) void k_mlp23(
    const float* __restrict__ z1, const float* __restrict__ W2,
    const float* __restrict__ b2, const float* __restrict__ W3,
    const float* __restrict__ b3, float* __restrict__ out)
{
    __shared__ float z1s[16][M1];   // 16 KB
    __shared__ float Wt[64 * M2];   // 32 KB
    __shared__ float z2s[16][M2];   // 8 KB
    const int tid = threadIdx.x;
    const int j = tid & 127, nsub = tid >> 7;
    const int ngroups = (NND + 15) / 16;
    for (int g = blockIdx.x; g < ngroups; g += gridDim.x) {
        const int n0 = g * 16;
        for (int i = tid; i < 16 * M1 / 4; i += 256) {
            int nn = i >> 6;
            int kk = (i & 63) * 4;
            int n = n0 + nn;
            float4 v = (n < NND) ? *(const float4*)(z1 + (size_t)n * M1 + kk)
                                 : make_float4(0.f, 0.f, 0.f, 0.f);
            *(float4*)&z1s[nn][kk] = v;
        }
        float acc[8];
        #pragma unroll
        for (int r = 0; r < 8; ++r) acc[r] = b2[j];
        for (int kt = 0; kt < 4; ++kt) {
            __syncthreads();
            for (int i = tid; i < 64 * M2 / 4; i += 256) {
                int row = (i * 4) >> 7;
                int col = (i * 4) & 127;
                *(float4*)&Wt[row * M2 + col] =
                    *(const float4*)(W2 + (size_t)(kt * 64 + row) * M2 + col);
            }
            __syncthreads();
            #pragma unroll 4
            for (int k = 0; k < 64; ++k) {
                float wv = Wt[k * M2 + j];
                #pragma unroll
                for (int r = 0; r < 8; ++r)
                    acc[r] = fmaf(z1s[nsub + 2 * r][kt * 64 + k], wv, acc[r]);
            }
        }
        #pragma unroll
        for (int r = 0; r < 8; ++r) z2s[nsub + 2 * r][j] = fmaxf(acc[r], 0.f);
        __syncthreads();
        const int wid = tid >> 6, lane = tid & 63;
        for (int nl = wid; nl < 16; nl += 4) {
            float sv = W3[lane] * z2s[nl][lane] + W3[64 + lane] * z2s[nl][64 + lane];
            #pragma unroll
            for (int off = 32; off; off >>= 1) sv += __shfl_xor(sv, off, 64);
            if (lane == 0) {
                int n = n0 + nl;
                if (n < NND) out[n] = sv + b3[0];
            }
        }
        __syncthreads();
    }
}

extern "C" void kernel_launch(void* const* d_in, const int* in_sizes, int n_in,
                              void* d_out, int out_size, void* d_ws, size_t ws_size,
                              hipStream_t stream) {
    const int*   x_cat   = (const int*)  d_in[0];
    const float* x_num   = (const float*)d_in[1];
    const float* x_coord = (const float*)d_in[2];
    const int*   eidx    = (const int*)  d_in[3];
    const float* emb     = (const float*)d_in[4];
    const float* fB      = (const float*)d_in[5];
    const float* pW      = (const float*)d_in[6];
    const float* pb      = (const float*)d_in[7];
    const float* gatW    = (const float*)d_in[8];
    const float* attS    = (const float*)d_in[9];
    const float* attD    = (const float*)d_in[10];
    const float* gatB    = (const float*)d_in[11];
    const float* bnG     = (const float*)d_in[12];
    const float* bnB     = (const float*)d_in[13];
    const float* W1      = (const float*)d_in[14];
    const float* b1      = (const float*)d_in[15];
    const float* W2      = (const float*)d_in[16];
    const float* b2      = (const float*)d_in[17];
    const float* W3      = (const float*)d_in[18];
    const float* b3      = (const float*)d_in[19];
    float* out = (float*)d_out;

    char* p = (char*)d_ws;
    float*    x     = (float*)p;    p += (size_t)NND * HID * 4;
    float*    h     = (float*)p;    p += (size_t)NND * 256 * 4;
    float*    alphS = (float*)p;    p += (size_t)NND * NH * 4;
    float*    alphD = (float*)p;    p += (size_t)NND * NH * 4;
    float*    ssum  = (float*)p;    p += (size_t)NND * NH * 4;
    float*    accum = (float*)p;    p += (size_t)NND * HID * 4;
    float*    bnst  = (float*)p;    p += 512;

    k_feat_proj<<<512, 256, 0, stream>>>(x_cat, x_num, x_coord, emb, fB, pW, pb, x);
    for (int l = 0; l < 2; ++l) {
        k_gat_h<<<512, 256, 0, stream>>>(x, gatW + (size_t)l * HID * 256, h);
        k_alpha<<<2048, 256, 0, stream>>>(h, attS + l * NH * HID, attD + l * NH * HID,
                                          alphS, alphD);
        k_init<<<2048, 256, 0, stream>>>(accum, ssum, bnst);
        k_edge_sum<<<(ETOT + 255) / 256, 256, 0, stream>>>(eidx, alphS, alphD, ssum);
        k_edge_scatter<<<8192, 256, 0, stream>>>(eidx, alphS, alphD, ssum, h, accum);
        k_gat_fin<<<1024, 256, 0, stream>>>(accum, gatB + l * HID, bnst);
        k_bn_apply<<<12500, 256, 0, stream>>>(accum, bnst, bnG + l * HID, bnB + l * HID, x);
    }
    k_mlp1<<<512, 256, 0, stream>>>(x, W1, b1, h);
    k_mlp23<<<512, 256, 0, stream>>>(h, W2, b2, W3, b3, out);
}

// Round 3
// 828.043 us; speedup vs baseline: 1.4318x; 1.0236x over previous
//
#include <hip/hip_runtime.h>
#include <hip/hip_bf16.h>

#define NND 50000
#define NCATS 3
#define VOC 1000
#define EDIM 16
#define NNUMF 16
#define FMAP 32
#define FIN 128          // 3*16 + 16 + 64
#define HID 64
#define NH 4
#define EB 400000
#define ETOT 450000      // EB + NND self loops
#define M1 256
#define M2 128
#define EPS_BN 1e-5f

__device__ __forceinline__ float lrelu(float x) { return x > 0.f ? x : 0.2f * x; }

// ================= CSR build (once; graph is identical for both layers) =================
__global__ void k_zero_deg(int* __restrict__ deg) {
    int i = blockIdx.x * blockDim.x + threadIdx.x;
    if (i < NND) deg[i] = 0;
}

__global__ void k_count(const int* __restrict__ ei, int* __restrict__ deg) {
    int e = blockIdx.x * blockDim.x + threadIdx.x;
    if (e >= ETOT) return;
    int d = (e < EB) ? ei[EB + e] : e - EB;
    atomicAdd(&deg[d], 1);
}

__global__ __launch_bounds__(1024) void k_scan(const int* __restrict__ deg,
                                               int* __restrict__ off, int* __restrict__ cur) {
    __shared__ int part[1024];
    const int t = threadIdx.x;
    const int CH = (NND + 1023) / 1024;   // 49
    const int base = t * CH;
    int s = 0;
    for (int j = 0; j < CH; ++j) { int i = base + j; if (i < NND) s += deg[i]; }
    part[t] = s;
    __syncthreads();
    for (int ofs = 1; ofs < 1024; ofs <<= 1) {
        int v = (t >= ofs) ? part[t - ofs] : 0;
        __syncthreads();
        part[t] += v;
        __syncthreads();
    }
    int run = part[t] - s;    // exclusive prefix of this chunk
    for (int j = 0; j < CH; ++j) {
        int i = base + j;
        if (i < NND) { off[i] = run; cur[i] = run; run += deg[i]; }
    }
    if (t == 0) off[NND] = ETOT;
}

__global__ void k_fill(const int* __restrict__ ei, int* __restrict__ cur,
                       int* __restrict__ srcs) {
    int e = blockIdx.x * blockDim.x + threadIdx.x;
    if (e >= ETOT) return;
    int s, d;
    if (e < EB) { s = ei[e]; d = ei[EB + e]; } else { s = d = e - EB; }
    int p = atomicAdd(&cur[d], 1);
    srcs[p] = s;
}

// ================= K1: featurize + project (128 -> 64), 16-node tiles =================
__global__ __launch_bounds__(256) void k_feat_proj(
    const int* __restrict__ x_cat, const float* __restrict__ x_num,
    const float* __restrict__ x_coord, const float* __restrict__ emb,
    const float* __restrict__ fB, const float* __restrict__ pW,
    const float* __restrict__ pb, float* __restrict__ xout)
{
    __shared__ float Wl[FIN * HID];   // 32 KB
    __shared__ float feat[16][FIN];   // 8 KB
    const int tid = threadIdx.x;
    for (int i = tid; i < FIN * HID; i += 256) Wl[i] = pW[i];
    const int wid = tid >> 6, lane = tid & 63;
    const int col = lane, ng = wid;
    const float bias = pb[col];
    const int ntiles = NND / 16;
    for (int t = blockIdx.x; t < ntiles; t += gridDim.x) {
        const int n0 = t * 16;
        __syncthreads();
        #pragma unroll
        for (int r = 0; r < 4; ++r) {
            const int nn = wid * 4 + r;
            const int n = n0 + nn;
            float v;
            if (lane < 48) {
                int c = lane >> 4, j = lane & 15;
                int idx = x_cat[n * NCATS + c];
                v = emb[((size_t)c * VOC + idx) * EDIM + j];
            } else {
                v = x_num[n * NNUMF + (lane - 48)];
            }
            feat[nn][lane] = v;
            float c0 = x_coord[n * 2 + 0], c1 = x_coord[n * 2 + 1];
            int f = lane & 31;
            float xp = 6.283185307179586f * (c0 * fB[f] + c1 * fB[FMAP + f]);
            feat[nn][64 + lane] = (lane < 32) ? sinf(xp) : cosf(xp);
        }
        __syncthreads();
        float acc[4] = {bias, bias, bias, bias};
        #pragma unroll 4
        for (int k = 0; k < FIN; ++k) {
            float w = Wl[k * HID + col];
            #pragma unroll
            for (int j = 0; j < 4; ++j)
                acc[j] = fmaf(feat[ng + 4 * j][k], w, acc[j]);
        }
        #pragma unroll
        for (int j = 0; j < 4; ++j)
            xout[(size_t)(n0 + ng + 4 * j) * HID + col] = acc[j];
    }
}

// ================= K2: h = x @ gatW (64 -> 256), float4 inner loop =================
__global__ __launch_bounds__(256) void k_gat_h(
    const float* __restrict__ x, const float* __restrict__ W, float* __restrict__ h)
{
    __shared__ float Wl[HID * 256];   // 64 KB
    __shared__ float xs[16][HID];     // 4 KB
    const int tid = threadIdx.x;
    for (int i = tid; i < HID * 256; i += 256) Wl[i] = W[i];
    const int ntiles = NND / 16;
    for (int t = blockIdx.x; t < ntiles; t += gridDim.x) {
        const int n0 = t * 16;
        __syncthreads();
        {
            int idx = tid * 4;
            int nn = idx >> 6, k = idx & 63;
            *(float4*)&xs[nn][k] = *(const float4*)(x + (size_t)(n0 + nn) * HID + k);
        }
        __syncthreads();
        float acc[16];
        #pragma unroll
        for (int nn = 0; nn < 16; ++nn) acc[nn] = 0.f;
        for (int k = 0; k < HID; k += 4) {
            float w0 = Wl[(k + 0) * 256 + tid];
            float w1 = Wl[(k + 1) * 256 + tid];
            float w2 = Wl[(k + 2) * 256 + tid];
            float w3 = Wl[(k + 3) * 256 + tid];
            #pragma unroll
            for (int nn = 0; nn < 16; ++nn) {
                float4 xv = *(const float4*)&xs[nn][k];
                acc[nn] = fmaf(xv.x, w0, fmaf(xv.y, w1, fmaf(xv.z, w2, fmaf(xv.w, w3, acc[nn]))));
            }
        }
        #pragma unroll
        for (int nn = 0; nn < 16; ++nn)
            h[(size_t)(n0 + nn) * 256 + tid] = acc[nn];
    }
}

// ================= K2a: va = W @ att (64x8) + zero bnst =================
__global__ __launch_bounds__(512) void k_va(
    const float* __restrict__ W, const float* __restrict__ aS,
    const float* __restrict__ aD, float* __restrict__ va, float* __restrict__ bnst)
{
    const int t = threadIdx.x;
    const int k = t >> 3, q = t & 7, hh = q & 3;
    const float* a = (q >= 4) ? aD : aS;
    float s = 0.f;
    #pragma unroll 8
    for (int d = 0; d < HID; ++d)
        s += W[k * 256 + hh * 64 + d] * a[hh * 64 + d];
    va[k * 8 + q] = s;
    if (t < 128) bnst[t] = 0.f;
}

// ================= K2b: alphas from x (12.8 MB read instead of 51 MB) =================
__global__ __launch_bounds__(256) void k_alpha2(
    const float* __restrict__ x, const float* __restrict__ va,
    float* __restrict__ alphS, float* __restrict__ alphD)
{
    __shared__ float vas[64 * 8];
    const int tid = threadIdx.x;
    for (int i = tid; i < 512; i += 256) vas[i] = va[i];
    __syncthreads();
    const int lane = tid & 63, wid = tid >> 6;
    const float4 vS = *(const float4*)&vas[lane * 8];
    const float4 vD = *(const float4*)&vas[lane * 8 + 4];
    for (int n = blockIdx.x * 4 + wid; n < NND; n += gridDim.x * 4) {
        float v = x[(size_t)n * HID + lane];
        float s0 = v * vS.x, s1 = v * vS.y, s2 = v * vS.z, s3 = v * vS.w;
        float d0 = v * vD.x, d1 = v * vD.y, d2 = v * vD.z, d3 = v * vD.w;
        #pragma unroll
        for (int ofs = 32; ofs; ofs >>= 1) {
            s0 += __shfl_xor(s0, ofs, 64); s1 += __shfl_xor(s1, ofs, 64);
            s2 += __shfl_xor(s2, ofs, 64); s3 += __shfl_xor(s3, ofs, 64);
            d0 += __shfl_xor(d0, ofs, 64); d1 += __shfl_xor(d1, ofs, 64);
            d2 += __shfl_xor(d2, ofs, 64); d3 += __shfl_xor(d3, ofs, 64);
        }
        if (lane == 0) {
            *(float4*)(alphS + (size_t)n * 4) = make_float4(s0, s1, s2, s3);
            *(float4*)(alphD + (size_t)n * 4) = make_float4(d0, d1, d2, d3);
        }
    }
}

// ================= K5: CSR aggregate (wave per dst) + finalize + BN stats =================
__global__ __launch_bounds__(256) void k_aggregate(
    const int* __restrict__ off, const int* __restrict__ srcs,
    const float* __restrict__ alphS, const float* __restrict__ alphD,
    const float* __restrict__ h, const float* __restrict__ gat_b,
    float* __restrict__ accum, float* __restrict__ bnst)
{
    const int tid = threadIdx.x, lane = tid & 63, wid = tid >> 6;
    const float bd = gat_b[lane];
    float s1 = 0.f, s2 = 0.f;
    for (int d = blockIdx.x * 4 + wid; d < NND; d += gridDim.x * 4) {
        const int o0 = off[d], o1 = off[d + 1];
        const int deg = o1 - o0;
        const float4 ad = *(const float4*)(alphD + (size_t)d * 4);
        float dn0 = 0.f, dn1 = 0.f, dn2 = 0.f, dn3 = 0.f;
        for (int i = lane; i < deg; i += 64) {
            int s = srcs[o0 + i];
            float4 as = *(const float4*)(alphS + (size_t)s * 4);
            dn0 += __expf(lrelu(as.x + ad.x));
            dn1 += __expf(lrelu(as.y + ad.y));
            dn2 += __expf(lrelu(as.z + ad.z));
            dn3 += __expf(lrelu(as.w + ad.w));
        }
        #pragma unroll
        for (int ofs = 32; ofs; ofs >>= 1) {
            dn0 += __shfl_xor(dn0, ofs, 64); dn1 += __shfl_xor(dn1, ofs, 64);
            dn2 += __shfl_xor(dn2, ofs, 64); dn3 += __shfl_xor(dn3, ofs, 64);
        }
        const float i0 = __fdividef(1.f, dn0 + 1e-16f);
        const float i1 = __fdividef(1.f, dn1 + 1e-16f);
        const float i2 = __fdividef(1.f, dn2 + 1e-16f);
        const float i3 = __fdividef(1.f, dn3 + 1e-16f);
        float acc = 0.f;
        for (int c0 = 0; c0 < deg; c0 += 64) {
            const int m = min(64, deg - c0);
            int sE = 0; float w0 = 0.f, w1 = 0.f, w2 = 0.f, w3 = 0.f;
            if (lane < m) {
                sE = srcs[o0 + c0 + lane];
                float4 as = *(const float4*)(alphS + (size_t)sE * 4);
                w0 = __expf(lrelu(as.x + ad.x)) * i0;
                w1 = __expf(lrelu(as.y + ad.y)) * i1;
                w2 = __expf(lrelu(as.z + ad.z)) * i2;
                w3 = __expf(lrelu(as.w + ad.w)) * i3;
            }
            for (int j = 0; j < m; ++j) {
                const int   sj = __shfl(sE, j, 64);
                const float a0 = __shfl(w0, j, 64), a1 = __shfl(w1, j, 64);
                const float a2 = __shfl(w2, j, 64), a3 = __shfl(w3, j, 64);
                const float* hs = h + (size_t)sj * 256;
                acc += a0 * hs[lane] + a1 * hs[64 + lane]
                     + a2 * hs[128 + lane] + a3 * hs[192 + lane];
            }
        }
        float g = acc * 0.25f + bd;
        accum[(size_t)d * HID + lane] = g;
        s1 += g; s2 += g * g;
    }
    __shared__ float red[2][256];
    red[0][tid] = s1; red[1][tid] = s2;
    __syncthreads();
    if (tid < 64) {
        float a = red[0][tid] + red[0][tid + 64] + red[0][tid + 128] + red[0][tid + 192];
        float b = red[1][tid] + red[1][tid + 64] + red[1][tid + 128] + red[1][tid + 192];
        atomicAdd(&bnst[tid], a);
        atomicAdd(&bnst[64 + tid], b);
    }
}

// ================= K7: BN apply + relu + residual (in place on x) =================
__global__ void k_bn_apply(const float* __restrict__ accum, const float* __restrict__ bnst,
                           const float* __restrict__ gamma, const float* __restrict__ beta,
                           float* __restrict__ x)
{
    int i = blockIdx.x * blockDim.x + threadIdx.x;
    if (i >= NND * HID) return;
    int d = i & 63;
    float mu = bnst[d] * (1.f / NND);
    float var = bnst[64 + d] * (1.f / NND) - mu * mu;
    float inv = rsqrtf(var + EPS_BN);
    float y = (accum[i] - mu) * inv * gamma[d] + beta[d];
    y = fmaxf(y, 0.f);
    x[i] = y + x[i];
}

// ================= K8: z1 = relu(x @ W1 + b1), float4 inner loop =================
__global__ __launch_bounds__(256) void k_mlp1(
    const float* __restrict__ x, const float* __restrict__ W1,
    const float* __restrict__ b1, float* __restrict__ z1)
{
    __shared__ float Wl[HID * M1];    // 64 KB
    __shared__ float xs[16][HID];     // 4 KB
    const int tid = threadIdx.x;
    for (int i = tid; i < HID * M1; i += 256) Wl[i] = W1[i];
    const float bias = b1[tid];
    const int ntiles = NND / 16;
    for (int t = blockIdx.x; t < ntiles; t += gridDim.x) {
        const int n0 = t * 16;
        __syncthreads();
        {
            int idx = tid * 4;
            int nn = idx >> 6, k = idx & 63;
            *(float4*)&xs[nn][k] = *(const float4*)(x + (size_t)(n0 + nn) * HID + k);
        }
        __syncthreads();
        float acc[16];
        #pragma unroll
        for (int nn = 0; nn < 16; ++nn) acc[nn] = bias;
        for (int k = 0; k < HID; k += 4) {
            float w0 = Wl[(k + 0) * M1 + tid];
            float w1 = Wl[(k + 1) * M1 + tid];
            float w2 = Wl[(k + 2) * M1 + tid];
            float w3 = Wl[(k + 3) * M1 + tid];
            #pragma unroll
            for (int nn = 0; nn < 16; ++nn) {
                float4 xv = *(const float4*)&xs[nn][k];
                acc[nn] = fmaf(xv.x, w0, fmaf(xv.y, w1, fmaf(xv.z, w2, fmaf(xv.w, w3, acc[nn]))));
            }
        }
        #pragma unroll
        for (int nn = 0; nn < 16; ++nn)
            z1[(size_t)(n0 + nn) * M1 + tid] = fmaxf(acc[nn], 0.f);
    }
}

// ================= K9: fused z2 = relu(z1@W2+b2); out = z2@W3+b3 (4x4 reg tiles) =================
#define NT2 32
__global__ __launch_bounds__(256) void k_mlp23(
    const float* __restrict__ z1, const float* __restrict__ W2,
    const float* __restrict__ b2, const float* __restrict__ W3,
    const float* __restrict__ b3, float* __restrict__ out)
{
    __shared__ float z1s[NT2][M1 + 4];   // 33.3 KB (row stride 260 floats, 16B-aligned)
    __shared__ float W2s[64][M2];        // 32 KB
    __shared__ float w3s[M2];
    const int tid = threadIdx.x;
    const int tj = tid & 31, tn = tid >> 5;
    if (tid < M2) w3s[tid] = W3[tid];
    const float bb3 = b3[0];
    float bias[4];
    #pragma unroll
    for (int jj = 0; jj < 4; ++jj) bias[jj] = b2[tj * 4 + jj];
    const int ntiles = (NND + NT2 - 1) / NT2;   // 1563
    for (int t = blockIdx.x; t < ntiles; t += gridDim.x) {
        const int n0 = t * NT2;
        __syncthreads();
        for (int i = tid; i < NT2 * 64; i += 256) {
            int nn = i >> 6, kk = (i & 63) * 4;
            int n = n0 + nn;
            float4 v = (n < NND) ? *(const float4*)(z1 + (size_t)n * M1 + kk)
                                 : make_float4(0.f, 0.f, 0.f, 0.f);
            *(float4*)&z1s[nn][kk] = v;
        }
        float acc[4][4];
        #pragma unroll
        for (int i = 0; i < 4; ++i)
            #pragma unroll
            for (int jj = 0; jj < 4; ++jj) acc[i][jj] = bias[jj];
        for (int kt = 0; kt < 4; ++kt) {
            __syncthreads();
            for (int i = tid; i < 64 * M2 / 4; i += 256) {
                int row = (i * 4) >> 7, col = (i * 4) & 127;
                *(float4*)&W2s[row][col] =
                    *(const float4*)(W2 + (size_t)(kt * 64 + row) * M2 + col);
            }
            __syncthreads();
            #pragma unroll 4
            for (int kk = 0; kk < 64; kk += 4) {
                float4 wv0 = *(const float4*)&W2s[kk + 0][tj * 4];
                float4 wv1 = *(const float4*)&W2s[kk + 1][tj * 4];
                float4 wv2 = *(const float4*)&W2s[kk + 2][tj * 4];
                float4 wv3 = *(const float4*)&W2s[kk + 3][tj * 4];
                #pragma unroll
                for (int i = 0; i < 4; ++i) {
                    float4 zv = *(const float4*)&z1s[tn * 4 + i][kt * 64 + kk];
                    acc[i][0] = fmaf(zv.x, wv0.x, acc[i][0]);
                    acc[i][1] = fmaf(zv.x, wv0.y, acc[i][1]);
                    acc[i][2] = fmaf(zv.x, wv0.z, acc[i][2]);
                    acc[i][3] = fmaf(zv.x, wv0.w, acc[i][3]);
                    acc[i][0] = fmaf(zv.y, wv1.x, acc[i][0]);
                    acc[i][1] = fmaf(zv.y, wv1.y, acc[i][1]);
                    acc[i][2] = fmaf(zv.y, wv1.z, acc[i][2]);
                    acc[i][3] = fmaf(zv.y, wv1.w, acc[i][3]);
                    acc[i][0] = fmaf(zv.z, wv2.x, acc[i][0]);
                    acc[i][1] = fmaf(zv.z, wv2.y, acc[i][1]);
                    acc[i][2] = fmaf(zv.z, wv2.z, acc[i][2]);
                    acc[i][3] = fmaf(zv.z, wv2.w, acc[i][3]);
                    acc[i][0] = fmaf(zv.w, wv3.x, acc[i][0]);
                    acc[i][1] = fmaf(zv.w, wv3.y, acc[i][1]);
                    acc[i][2] = fmaf(zv.w, wv3.z, acc[i][2]);
                    acc[i][3] = fmaf(zv.w, wv3.w, acc[i][3]);
                }
            }
        }
        float p[4];
        #pragma unroll
        for (int i = 0; i < 4; ++i) {
            p[i] = fmaxf(acc[i][0], 0.f) * w3s[tj * 4 + 0]
                 + fmaxf(acc[i][1], 0.f) * w3s[tj * 4 + 1]
                 + fmaxf(acc[i][2], 0.f) * w3s[tj * 4 + 2]
                 + fmaxf(acc[i][3], 0.f) * w3s[tj * 4 + 3];
        }
        #pragma unroll
        for (int ofs = 16; ofs; ofs >>= 1) {
            #pragma unroll
            for (int i = 0; i < 4; ++i) p[i] += __shfl_xor(p[i], ofs, 64);
        }
        if (tj == 0) {
            #pragma unroll
            for (int i = 0; i < 4; ++i) {
                int n = n0 + tn * 4 + i;
                if (n < NND) out[n] = p[i] + bb3;
            }
        }
    }
}

extern "C" void kernel_launch(void* const* d_in, const int* in_sizes, int n_in,
                              void* d_out, int out_size, void* d_ws, size_t ws_size,
                              hipStream_t stream) {
    const int*   x_cat   = (const int*)  d_in[0];
    const float* x_num   = (const float*)d_in[1];
    const float* x_coord = (const float*)d_in[2];
    const int*   eidx    = (const int*)  d_in[3];
    const float* emb     = (const float*)d_in[4];
    const float* fB      = (const float*)d_in[5];
    const float* pW      = (const float*)d_in[6];
    const float* pb      = (const float*)d_in[7];
    const float* gatW    = (const float*)d_in[8];
    const float* attS    = (const float*)d_in[9];
    const float* attD    = (const float*)d_in[10];
    const float* gatB    = (const float*)d_in[11];
    const float* bnG     = (const float*)d_in[12];
    const float* bnB     = (const float*)d_in[13];
    const float* W1      = (const float*)d_in[14];
    const float* b1      = (const float*)d_in[15];
    const float* W2      = (const float*)d_in[16];
    const float* b2      = (const float*)d_in[17];
    const float* W3      = (const float*)d_in[18];
    const float* b3      = (const float*)d_in[19];
    float* out = (float*)d_out;

    char* p = (char*)d_ws;
    float* x     = (float*)p;  p += (size_t)NND * HID * 4;
    float* h     = (float*)p;  p += (size_t)NND * 256 * 4;
    float* alphS = (float*)p;  p += (size_t)NND * NH * 4;
    float* alphD = (float*)p;  p += (size_t)NND * NH * 4;
    float* accum = (float*)p;  p += (size_t)NND * HID * 4;
    float* bnst  = (float*)p;  p += 512;
    float* va    = (float*)p;  p += 512 * 4;
    int*   deg   = (int*)p;    p += (size_t)NND * 4;
    int*   cur   = (int*)p;    p += (size_t)NND * 4;
    int*   off   = (int*)p;    p += (size_t)(NND + 1) * 4 + 4;
    int*   srcs  = (int*)p;    p += (size_t)ETOT * 4;

    // CSR build (graph constant across layers)
    k_zero_deg<<<(NND + 255) / 256, 256, 0, stream>>>(deg);
    k_count<<<(ETOT + 255) / 256, 256, 0, stream>>>(eidx, deg);
    k_scan<<<1, 1024, 0, stream>>>(deg, off, cur);
    k_fill<<<(ETOT + 255) / 256, 256, 0, stream>>>(eidx, cur, srcs);

    k_feat_proj<<<512, 256, 0, stream>>>(x_cat, x_num, x_coord, emb, fB, pW, pb, x);
    for (int l = 0; l < 2; ++l) {
        k_va<<<1, 512, 0, stream>>>(gatW + (size_t)l * HID * 256,
                                    attS + l * NH * HID, attD + l * NH * HID, va, bnst);
        k_gat_h<<<625, 256, 0, stream>>>(x, gatW + (size_t)l * HID * 256, h);
        k_alpha2<<<2048, 256, 0, stream>>>(x, va, alphS, alphD);
        k_aggregate<<<1024, 256, 0, stream>>>(off, srcs, alphS, alphD, h,
                                              gatB + l * HID, accum, bnst);
        k_bn_apply<<<12500, 256, 0, stream>>>(accum, bnst, bnG + l * HID, bnB + l * HID, x);
    }
    k_mlp1<<<625, 256, 0, stream>>>(x, W1, b1, h);
    k_mlp23<<<521, 256, 0, stream>>>(h, W2, b2, W3, b3, out);
}